// Round 13
// baseline (4360.405 us; speedup 1.0000x reference)
//
#include <hip/hip_runtime.h>
#include <hip/hip_bf16.h>
#include <cstdint>
#include <cstddef>

#define B 64
#define T 512
#define EMBED 128
#define H 128
#define G4 512          // 4*H
#define HOUT 256        // 2*H (bilstm concat)
#define NUM_CLASSES 10
#define BT (B * T)      // 32768

typedef float v2f __attribute__((ext_vector_type(2)));
typedef float v4f __attribute__((ext_vector_type(4)));
typedef short v8s __attribute__((ext_vector_type(8)));       // 8 bf16

// ---------------------------------------------------------------------------
// bf16 split helpers (truncation; hi+lo ~ 2^-17 relative)
// ---------------------------------------------------------------------------
__device__ __forceinline__ unsigned short bf16_hi(float v) {
    return (unsigned short)(__float_as_uint(v) >> 16);
}
__device__ __forceinline__ unsigned short bf16_lo(float v, unsigned short hi) {
    float hf = __uint_as_float((unsigned)hi << 16);
    return (unsigned short)(__float_as_uint(v - hf) >> 16);
}

// ---------------------------------------------------------------------------
// 1a) prep_w2t: w2t[n][j] bf16, n in [0,1024): col n of (n<512 ? Wf : Wb).
// ---------------------------------------------------------------------------
__global__ __launch_bounds__(128) void prep_w2t_kernel(
    const float* __restrict__ Wf, const float* __restrict__ Wb,
    unsigned short* __restrict__ w2t, int K)
{
    int n = blockIdx.x;
    const float* src = (n < 512) ? (Wf + n) : (Wb + (n - 512));
    unsigned short* dst = w2t + (size_t)n * (2 * K);
    for (int j = threadIdx.x; j < K; j += 128) {
        float v = src[(size_t)j * G4];
        unsigned short hi = bf16_hi(v);
        dst[j]     = hi;
        dst[K + j] = bf16_lo(v, hi);
    }
}

// ---------------------------------------------------------------------------
// 1b) prep_a2_emb: a2[m][0..128)=hi(emb[x[m]][j]), [128..256)=lo. K=128.
// ---------------------------------------------------------------------------
__global__ __launch_bounds__(128) void prep_a2_emb_kernel(
    const int* __restrict__ x, const float* __restrict__ emb,
    unsigned short* __restrict__ a2)
{
    int m = blockIdx.x;
    int j = threadIdx.x;
    float v = emb[(size_t)x[m] * EMBED + j];
    unsigned short hi = bf16_hi(v);
    a2[(size_t)m * 256 + j]       = hi;
    a2[(size_t)m * 256 + 128 + j] = bf16_lo(v, hi);
}

// ---------------------------------------------------------------------------
// 1c) prep_a2_h: from H0 (BT x 256 f32). a2 row = [hi(256) | lo(256)].
// ---------------------------------------------------------------------------
__global__ __launch_bounds__(256) void prep_a2_h_kernel(
    const float* __restrict__ H0, unsigned short* __restrict__ a2)
{
    int m = blockIdx.x;
    int j = threadIdx.x;
    float v = H0[(size_t)m * 256 + j];
    unsigned short hi = bf16_hi(v);
    a2[(size_t)m * 512 + j]       = hi;
    a2[(size_t)m * 512 + 256 + j] = bf16_lo(v, hi);
}

// ---------------------------------------------------------------------------
// 2) MFMA GEMM (r11, unchanged): C = A @ [Wf|Wb] + bias via 3-term bf16
//    split. 128x128 tile, 4 waves, 16x16x32 bf16 MFMA.
// ---------------------------------------------------------------------------
__global__ __launch_bounds__(256) void gemm_mfma_kernel(
    const unsigned short* __restrict__ a2, const unsigned short* __restrict__ w2t,
    const float* __restrict__ bF, const float* __restrict__ bB,
    float* __restrict__ xpF, float* __restrict__ xpB, int K)
{
    __shared__ __align__(16) unsigned short As[128 * 40];
    __shared__ __align__(16) unsigned short Ws[128 * 40];

    const int tid  = threadIdx.x;
    const int lane = tid & 63;
    const int wv   = tid >> 6;
    const int wr   = wv >> 1;
    const int wc   = wv & 1;
    const int n0   = blockIdx.x * 128;
    const int m0   = blockIdx.y * 128;
    const int K2   = 2 * K;

    const int srow  = tid >> 1;
    const int spart = tid & 1;
    const unsigned short* agp = a2 + (size_t)(m0 + srow) * K2 + spart * 16;
    const unsigned short* wgp = w2t + (size_t)(n0 + srow) * K2 + spart * 16;
    unsigned short* alp = &As[srow * 40 + spart * 16];
    unsigned short* wlp = &Ws[srow * 40 + spart * 16];

    v4f acc[4][4];
#pragma unroll
    for (int i = 0; i < 4; i++)
#pragma unroll
        for (int j = 0; j < 4; j++) acc[i][j] = (v4f){0.f, 0.f, 0.f, 0.f};

    const int ksub = K >> 5;
    const int nsteps = 3 * ksub;
    for (int s = 0; s < nsteps; ++s) {
        int t  = s / ksub;
        int kk = s - t * ksub;
        int aoff = ((t == 2) ? K : 0) + kk * 32;
        int woff = ((t == 1) ? K : 0) + kk * 32;

        {
            v8s a0 = *(const v8s*)(agp + aoff);
            v8s a1 = *(const v8s*)(agp + aoff + 8);
            v8s w0 = *(const v8s*)(wgp + woff);
            v8s w1 = *(const v8s*)(wgp + woff + 8);
            *(v8s*)(alp)     = a0;
            *(v8s*)(alp + 8) = a1;
            *(v8s*)(wlp)     = w0;
            *(v8s*)(wlp + 8) = w1;
        }
        __syncthreads();

        v8s af[4], wf[4];
#pragma unroll
        for (int mr = 0; mr < 4; mr++)
            af[mr] = *(const v8s*)&As[(wr * 64 + mr * 16 + (lane & 15)) * 40 + (lane >> 4) * 8];
#pragma unroll
        for (int nr = 0; nr < 4; nr++)
            wf[nr] = *(const v8s*)&Ws[(wc * 64 + nr * 16 + (lane & 15)) * 40 + (lane >> 4) * 8];
#pragma unroll
        for (int mr = 0; mr < 4; mr++)
#pragma unroll
            for (int nr = 0; nr < 4; nr++)
                acc[mr][nr] = __builtin_amdgcn_mfma_f32_16x16x32_bf16(
                    af[mr], wf[nr], acc[mr][nr], 0, 0, 0);
        __syncthreads();
    }

#pragma unroll
    for (int nr = 0; nr < 4; nr++) {
        int gcol = n0 + wc * 64 + nr * 16 + (lane & 15);
        float bv = (gcol < 512) ? bF[gcol] : bB[gcol - 512];
        float* dst = (gcol < 512) ? (xpF + gcol) : (xpB + gcol - 512);
#pragma unroll
        for (int mr = 0; mr < 4; mr++) {
            int grow = m0 + wr * 64 + mr * 16 + (lane >> 4) * 4;
            v4f fr = acc[mr][nr];
#pragma unroll
            for (int r = 0; r < 4; r++)
                dst[(size_t)(grow + r) * G4] = fr[r] + bv;
        }
    }
}

// ---------------------------------------------------------------------------
// 3) LSTM scan v11: PAIRED v6. One WG of 1024 threads handles BOTH
//    directions of one batch element: threads [0,512) = forward, [512,1024)
//    = backward. The two halves' dep chains are data-independent, so each
//    SIMD interleaves 4 waves of two different phases -> the ~1120-cyc
//    per-step latency constant (ds_read + DPP + transcendental chains +
//    barrier skew) is paid ~once for two problem-steps instead of twice.
//    Inner structure per half = v6 verbatim (353 us known-good): f32
//    pk_fma, f32 register weights (asm-pinned), DPP butterfly, LDS-only
//    barrier drain, double-buffered f32 h.
// ---------------------------------------------------------------------------
__device__ __forceinline__ float fast_sig(float x) {
    float e = __expf(-x);
    return __builtin_amdgcn_rcpf(1.f + e);
}

template <int CTRL>
__device__ __forceinline__ float dpp_add(float x) {
    int y = __builtin_amdgcn_mov_dpp(__float_as_int(x), CTRL, 0xF, 0xF, true);
    return x + __int_as_float(y);
}

__device__ __forceinline__ void wg_barrier_lds() {
    asm volatile("s_waitcnt lgkmcnt(0)" ::: "memory");
    __builtin_amdgcn_s_barrier();
}

#define PKFMA(acc, h2, w2) \
    asm("v_pk_fma_f32 %0, %1, %2, %0" : "+v"(acc) : "v"(h2), "v"(w2))

__global__ __launch_bounds__(1024) __attribute__((amdgpu_waves_per_eu(4, 4)))
void lstm_scan_kernel(
    const float* __restrict__ xp0, const float* __restrict__ xp1,
    const float* __restrict__ Wh0, const float* __restrict__ Wh1,
    const int* __restrict__ x, float* __restrict__ hout)
{
    const int b   = blockIdx.x;
    const int tid = threadIdx.x;
    const int sub = tid >> 9;          // 0 = forward, 1 = backward
    const int stid = tid & 511;
    const float* __restrict__ xp = sub ? xp1 : xp0;
    const float* __restrict__ Wh = sub ? Wh1 : Wh0;

    const int ks  = stid & 3;
    const int q   = stid >> 2;

    const float* wp = Wh + (size_t)(ks * 32) * G4 + q;
#define LDP(c, p) v2f w##c##_##p = { wp[(2 * p) * G4 + c * H], \
                                     wp[(2 * p + 1) * G4 + c * H] }
#define DECLC(c) \
    LDP(c, 0);  LDP(c, 1);  LDP(c, 2);  LDP(c, 3);  \
    LDP(c, 4);  LDP(c, 5);  LDP(c, 6);  LDP(c, 7);  \
    LDP(c, 8);  LDP(c, 9);  LDP(c, 10); LDP(c, 11); \
    LDP(c, 12); LDP(c, 13); LDP(c, 14); LDP(c, 15);
    DECLC(0) DECLC(1) DECLC(2) DECLC(3)
#undef DECLC
#undef LDP
#define PIN4(a, b_, c_, d_) asm volatile("" : "+v"(a), "+v"(b_), "+v"(c_), "+v"(d_))
#define PINC(c) \
    PIN4(w##c##_0,  w##c##_1,  w##c##_2,  w##c##_3);  \
    PIN4(w##c##_4,  w##c##_5,  w##c##_6,  w##c##_7);  \
    PIN4(w##c##_8,  w##c##_9,  w##c##_10, w##c##_11); \
    PIN4(w##c##_12, w##c##_13, w##c##_14, w##c##_15)
    PINC(0); PINC(1); PINC(2); PINC(3);
#undef PINC
#undef PIN4

    // h: [dir][buf][block ks][32 data + 4 skew]; per-wave reads stay the
    // 4-address bank-disjoint v6 pattern (dir offset = 288 floats = 0 mod 32).
    __shared__ __align__(16) float h_sh[2][2][4][36];
    __shared__ unsigned char mask_sh[T];

    if (stid < H) h_sh[sub][0][stid >> 5][stid & 31] = 0.f;
    if (tid < T) mask_sh[tid] = (x[(size_t)b * T + tid] != 0) ? 1 : 0;
    float c_reg = 0.f, h_reg = 0.f;
    __syncthreads();

    const int t0 = sub ? T - 1 : 0;
    const ptrdiff_t dstep = sub ? -(ptrdiff_t)G4 : (ptrdiff_t)G4;
    const ptrdiff_t hstep = sub ? -(ptrdiff_t)HOUT : (ptrdiff_t)HOUT;
    const float* xptr = xp + ((size_t)b * T + t0) * G4 + ks * H + q;
    float*       hptr = hout + ((size_t)b * T + t0) * HOUT + sub * H + q;
    float xp_cur = *xptr;

    int cb = 0;
    int t = t0;
    const int tinc = sub ? -1 : 1;

    for (int s = 0; s < T; s++) {
        float xin = xp_cur;
        if (s + 1 < T) {
            xptr += dstep;
            xp_cur = *xptr;
        }

        v2f acc0 = { (ks == 0) ? xin : 0.f, 0.f };
        v2f acc1 = { (ks == 1) ? xin : 0.f, 0.f };
        v2f acc2 = { (ks == 2) ? xin : 0.f, 0.f };
        v2f acc3 = { (ks == 3) ? xin : 0.f, 0.f };

        const v4f* hp = (const v4f*)&h_sh[sub][cb][ks][0];
#define STEP4(kk, pA, pB) { \
        v4f hv = hp[kk]; \
        v2f h01 = __builtin_shufflevector(hv, hv, 0, 1); \
        v2f h23 = __builtin_shufflevector(hv, hv, 2, 3); \
        PKFMA(acc0, h01, w0_##pA); PKFMA(acc0, h23, w0_##pB); \
        PKFMA(acc1, h01, w1_##pA); PKFMA(acc1, h23, w1_##pB); \
        PKFMA(acc2, h01, w2_##pA); PKFMA(acc2, h23, w2_##pB); \
        PKFMA(acc3, h01, w3_##pA); PKFMA(acc3, h23, w3_##pB); }
        STEP4(0, 0, 1)   STEP4(1, 2, 3)   STEP4(2, 4, 5)   STEP4(3, 6, 7)
        STEP4(4, 8, 9)   STEP4(5, 10, 11) STEP4(6, 12, 13) STEP4(7, 14, 15)
#undef STEP4

        float a0 = acc0.x + acc0.y;
        float a1 = acc1.x + acc1.y;
        float a2 = acc2.x + acc2.y;
        float a3 = acc3.x + acc3.y;

        a0 = dpp_add<0xB1>(a0); a1 = dpp_add<0xB1>(a1);
        a2 = dpp_add<0xB1>(a2); a3 = dpp_add<0xB1>(a3);
        a0 = dpp_add<0x4E>(a0); a1 = dpp_add<0x4E>(a1);
        a2 = dpp_add<0x4E>(a2); a3 = dpp_add<0x4E>(a3);

        float ig = fast_sig(a0);
        float fg = fast_sig(a1);
        float gg = 2.f * fast_sig(a2 + a2) - 1.f;
        float og = fast_sig(a3);
        float cn = fmaf(fg, c_reg, ig * gg);
        float th = 2.f * fast_sig(cn + cn) - 1.f;
        float hn = og * th;

        bool msk = mask_sh[t] != 0;
        c_reg = msk ? cn : c_reg;
        h_reg = msk ? hn : h_reg;

        if (ks == 0) {
            h_sh[sub][cb ^ 1][q >> 5][q & 31] = h_reg;
            *hptr = h_reg;
        }
        hptr += hstep;
        wg_barrier_lds();
        cb ^= 1;
        t += tinc;
    }
}

// ---------------------------------------------------------------------------
// 4) pooling: per (b,t) max & mean over 256 channels -> feat (B, 2T)
// ---------------------------------------------------------------------------
__global__ __launch_bounds__(256) void pool_kernel(
    const float* __restrict__ Hin, float* __restrict__ feat)
{
    int wave = threadIdx.x >> 6;
    int lane = threadIdx.x & 63;
    int bt = blockIdx.x * 4 + wave;
    float4 v = *(const float4*)&Hin[(size_t)bt * HOUT + lane * 4];
    float mx = fmaxf(fmaxf(v.x, v.y), fmaxf(v.z, v.w));
    float sm = (v.x + v.y) + (v.z + v.w);
#pragma unroll
    for (int off = 32; off > 0; off >>= 1) {
        mx = fmaxf(mx, __shfl_down(mx, off));
        sm += __shfl_down(sm, off);
    }
    if (lane == 0) {
        int b = bt >> 9;
        int t = bt & (T - 1);
        feat[(size_t)b * (2 * T) + t]     = mx;
        feat[(size_t)b * (2 * T) + T + t] = sm * (1.f / 256.f);
    }
}

// ---------------------------------------------------------------------------
// 5) FC: out(B,10) = relu(feat(B,1024) @ fcW(1024,10) + fcb)
// ---------------------------------------------------------------------------
__global__ __launch_bounds__(128) void fc_kernel(
    const float* __restrict__ feat, const float* __restrict__ fcW,
    const float* __restrict__ fcb, float* __restrict__ out)
{
    __shared__ float red[2][NUM_CLASSES];
    int b = blockIdx.x, tid = threadIdx.x;
    float acc[NUM_CLASSES];
#pragma unroll
    for (int c = 0; c < NUM_CLASSES; c++) acc[c] = 0.f;
#pragma unroll
    for (int it = 0; it < 8; it++) {
        int k = tid + it * 128;
        float fv = feat[(size_t)b * 1024 + k];
#pragma unroll
        for (int c = 0; c < NUM_CLASSES; c++)
            acc[c] = fmaf(fv, fcW[(size_t)k * NUM_CLASSES + c], acc[c]);
    }
#pragma unroll
    for (int c = 0; c < NUM_CLASSES; c++) {
        float v = acc[c];
        for (int off = 32; off > 0; off >>= 1) v += __shfl_down(v, off);
        if ((tid & 63) == 0) red[tid >> 6][c] = v;
    }
    __syncthreads();
    if (tid < NUM_CLASSES) {
        float v = red[0][tid] + red[1][tid] + fcb[tid];
        out[(size_t)b * NUM_CLASSES + tid] = fmaxf(v, 0.f);
    }
}

// ---------------------------------------------------------------------------
// launch
// ws layout (MiB): [0,32) Hbuf | [32,96) xpF | [96,160) xpB |
// [160,192) a2 | [192,193) w2t | [193,193.25) feat
// ---------------------------------------------------------------------------
extern "C" void kernel_launch(void* const* d_in, const int* in_sizes, int n_in,
                              void* d_out, int out_size, void* d_ws, size_t ws_size,
                              hipStream_t stream)
{
    const int*   x     = (const int*)d_in[0];
    const float* emb   = (const float*)d_in[1];
    const float* Wx_f0 = (const float*)d_in[2];
    const float* Wh_f0 = (const float*)d_in[3];
    const float* b_f0  = (const float*)d_in[4];
    const float* Wx_b0 = (const float*)d_in[5];
    const float* Wh_b0 = (const float*)d_in[6];
    const float* b_b0  = (const float*)d_in[7];
    const float* Wx_f1 = (const float*)d_in[8];
    const float* Wh_f1 = (const float*)d_in[9];
    const float* b_f1  = (const float*)d_in[10];
    const float* Wx_b1 = (const float*)d_in[11];
    const float* Wh_b1 = (const float*)d_in[12];
    const float* b_b1  = (const float*)d_in[13];
    const float* fcW   = (const float*)d_in[14];
    const float* fcb   = (const float*)d_in[15];
    float* out = (float*)d_out;

    char* ws = (char*)d_ws;
    const size_t MB = 1024 * 1024;
    float*          Hbuf = (float*)(ws);
    float*          xpF  = (float*)(ws + 32 * MB);
    float*          xpB  = (float*)(ws + 96 * MB);
    unsigned short* a2   = (unsigned short*)(ws + 160 * MB);
    unsigned short* w2t  = (unsigned short*)(ws + 192 * MB);
    float*          feat = (float*)(ws + 193 * MB);

    dim3 ggrid(1024 / 128, BT / 128);  // (8, 256)

    // ---- layer 0 (K = 128) ----
    prep_w2t_kernel<<<1024, 128, 0, stream>>>(Wx_f0, Wx_b0, w2t, EMBED);
    prep_a2_emb_kernel<<<BT, 128, 0, stream>>>(x, emb, a2);
    gemm_mfma_kernel<<<ggrid, 256, 0, stream>>>(a2, w2t, b_f0, b_b0, xpF, xpB, EMBED);
    lstm_scan_kernel<<<B, 1024, 0, stream>>>(xpF, xpB, Wh_f0, Wh_b0, x, Hbuf);

    // ---- layer 1 (K = 256) ----
    prep_w2t_kernel<<<1024, 128, 0, stream>>>(Wx_f1, Wx_b1, w2t, 2 * H);
    prep_a2_h_kernel<<<BT, 256, 0, stream>>>(Hbuf, a2);
    gemm_mfma_kernel<<<ggrid, 256, 0, stream>>>(a2, w2t, b_f1, b_b1, xpF, xpB, 2 * H);
    lstm_scan_kernel<<<B, 1024, 0, stream>>>(xpF, xpB, Wh_f1, Wh_b1, x, Hbuf);

    // ---- pooling + FC ----
    pool_kernel<<<BT / 4, 256, 0, stream>>>(Hbuf, feat);
    fc_kernel<<<B, 128, 0, stream>>>(feat, fcW, fcb, out);
}

// Round 14
// 871.809 us; speedup vs baseline: 5.0016x; 5.0016x over previous
//
#include <hip/hip_runtime.h>
#include <hip/hip_bf16.h>
#include <cstdint>
#include <cstddef>

#define B 64
#define T 512
#define EMBED 128
#define H 128
#define G4 512          // 4*H
#define HOUT 256        // 2*H (bilstm concat)
#define NUM_CLASSES 10
#define BT (B * T)      // 32768

typedef float v2f __attribute__((ext_vector_type(2)));
typedef float v4f __attribute__((ext_vector_type(4)));
typedef short v8s __attribute__((ext_vector_type(8)));       // 8 bf16

// ---------------------------------------------------------------------------
// bf16 split helpers (truncation; hi+lo ~ 2^-17 relative)
// ---------------------------------------------------------------------------
__device__ __forceinline__ unsigned short bf16_hi(float v) {
    return (unsigned short)(__float_as_uint(v) >> 16);
}
__device__ __forceinline__ unsigned short bf16_lo(float v, unsigned short hi) {
    float hf = __uint_as_float((unsigned)hi << 16);
    return (unsigned short)(__float_as_uint(v - hf) >> 16);
}

// ---------------------------------------------------------------------------
// 1a) prep_w2t: w2t[n][j] bf16, n in [0,1024): col n of (n<512 ? Wf : Wb).
// ---------------------------------------------------------------------------
__global__ __launch_bounds__(128) void prep_w2t_kernel(
    const float* __restrict__ Wf, const float* __restrict__ Wb,
    unsigned short* __restrict__ w2t, int K)
{
    int n = blockIdx.x;
    const float* src = (n < 512) ? (Wf + n) : (Wb + (n - 512));
    unsigned short* dst = w2t + (size_t)n * (2 * K);
    for (int j = threadIdx.x; j < K; j += 128) {
        float v = src[(size_t)j * G4];
        unsigned short hi = bf16_hi(v);
        dst[j]     = hi;
        dst[K + j] = bf16_lo(v, hi);
    }
}

// ---------------------------------------------------------------------------
// 1b) prep_a2_emb: a2[m][0..128)=hi(emb[x[m]][j]), [128..256)=lo. K=128.
// ---------------------------------------------------------------------------
__global__ __launch_bounds__(128) void prep_a2_emb_kernel(
    const int* __restrict__ x, const float* __restrict__ emb,
    unsigned short* __restrict__ a2)
{
    int m = blockIdx.x;
    int j = threadIdx.x;
    float v = emb[(size_t)x[m] * EMBED + j];
    unsigned short hi = bf16_hi(v);
    a2[(size_t)m * 256 + j]       = hi;
    a2[(size_t)m * 256 + 128 + j] = bf16_lo(v, hi);
}

// ---------------------------------------------------------------------------
// 1c) prep_a2_h: from H0 (BT x 256 f32). a2 row = [hi(256) | lo(256)].
// ---------------------------------------------------------------------------
__global__ __launch_bounds__(256) void prep_a2_h_kernel(
    const float* __restrict__ H0, unsigned short* __restrict__ a2)
{
    int m = blockIdx.x;
    int j = threadIdx.x;
    float v = H0[(size_t)m * 256 + j];
    unsigned short hi = bf16_hi(v);
    a2[(size_t)m * 512 + j]       = hi;
    a2[(size_t)m * 512 + 256 + j] = bf16_lo(v, hi);
}

// ---------------------------------------------------------------------------
// 2) MFMA GEMM (r11, unchanged): C = A @ [Wf|Wb] + bias via 3-term bf16
//    split: Ah@Wh + Ah@Wl + Al@Wh. 128x128 tile, 4 waves, 16x16x32 bf16.
// ---------------------------------------------------------------------------
__global__ __launch_bounds__(256) void gemm_mfma_kernel(
    const unsigned short* __restrict__ a2, const unsigned short* __restrict__ w2t,
    const float* __restrict__ bF, const float* __restrict__ bB,
    float* __restrict__ xpF, float* __restrict__ xpB, int K)
{
    __shared__ __align__(16) unsigned short As[128 * 40];
    __shared__ __align__(16) unsigned short Ws[128 * 40];

    const int tid  = threadIdx.x;
    const int lane = tid & 63;
    const int wv   = tid >> 6;
    const int wr   = wv >> 1;
    const int wc   = wv & 1;
    const int n0   = blockIdx.x * 128;
    const int m0   = blockIdx.y * 128;
    const int K2   = 2 * K;

    const int srow  = tid >> 1;
    const int spart = tid & 1;
    const unsigned short* agp = a2 + (size_t)(m0 + srow) * K2 + spart * 16;
    const unsigned short* wgp = w2t + (size_t)(n0 + srow) * K2 + spart * 16;
    unsigned short* alp = &As[srow * 40 + spart * 16];
    unsigned short* wlp = &Ws[srow * 40 + spart * 16];

    v4f acc[4][4];
#pragma unroll
    for (int i = 0; i < 4; i++)
#pragma unroll
        for (int j = 0; j < 4; j++) acc[i][j] = (v4f){0.f, 0.f, 0.f, 0.f};

    const int ksub = K >> 5;
    const int nsteps = 3 * ksub;
    for (int s = 0; s < nsteps; ++s) {
        int t  = s / ksub;
        int kk = s - t * ksub;
        int aoff = ((t == 2) ? K : 0) + kk * 32;
        int woff = ((t == 1) ? K : 0) + kk * 32;

        {
            v8s a0 = *(const v8s*)(agp + aoff);
            v8s a1 = *(const v8s*)(agp + aoff + 8);
            v8s w0 = *(const v8s*)(wgp + woff);
            v8s w1 = *(const v8s*)(wgp + woff + 8);
            *(v8s*)(alp)     = a0;
            *(v8s*)(alp + 8) = a1;
            *(v8s*)(wlp)     = w0;
            *(v8s*)(wlp + 8) = w1;
        }
        __syncthreads();

        v8s af[4], wf[4];
#pragma unroll
        for (int mr = 0; mr < 4; mr++)
            af[mr] = *(const v8s*)&As[(wr * 64 + mr * 16 + (lane & 15)) * 40 + (lane >> 4) * 8];
#pragma unroll
        for (int nr = 0; nr < 4; nr++)
            wf[nr] = *(const v8s*)&Ws[(wc * 64 + nr * 16 + (lane & 15)) * 40 + (lane >> 4) * 8];
#pragma unroll
        for (int mr = 0; mr < 4; mr++)
#pragma unroll
            for (int nr = 0; nr < 4; nr++)
                acc[mr][nr] = __builtin_amdgcn_mfma_f32_16x16x32_bf16(
                    af[mr], wf[nr], acc[mr][nr], 0, 0, 0);
        __syncthreads();
    }

#pragma unroll
    for (int nr = 0; nr < 4; nr++) {
        int gcol = n0 + wc * 64 + nr * 16 + (lane & 15);
        float bv = (gcol < 512) ? bF[gcol] : bB[gcol - 512];
        float* dst = (gcol < 512) ? (xpF + gcol) : (xpB + gcol - 512);
#pragma unroll
        for (int mr = 0; mr < 4; mr++) {
            int grow = m0 + wr * 64 + mr * 16 + (lane >> 4) * 4;
            v4f fr = acc[mr][nr];
#pragma unroll
            for (int r = 0; r < 4; r++)
                dst[(size_t)(grow + r) * G4] = fr[r] + bv;
        }
    }
}

// ---------------------------------------------------------------------------
// 3) LSTM scan v6 (r6/r11 verbatim, 353 us known-good): one WG (512 thr,
//    8 waves) per (batch, direction). tid = q*4 + ks; f32 pk_fma with f32
//    register weights (asm-pinned, waves_per_eu(2,2) -> 8 waves/CU fits
//    the register file; 1024-thr variants spill -- r2/r13); DPP butterfly;
//    bank-disjoint skewed h blocks; LDS-only barrier drain.
// ---------------------------------------------------------------------------
__device__ __forceinline__ float fast_sig(float x) {
    float e = __expf(-x);
    return __builtin_amdgcn_rcpf(1.f + e);
}

template <int CTRL>
__device__ __forceinline__ float dpp_add(float x) {
    int y = __builtin_amdgcn_mov_dpp(__float_as_int(x), CTRL, 0xF, 0xF, true);
    return x + __int_as_float(y);
}

__device__ __forceinline__ void wg_barrier_lds() {
    asm volatile("s_waitcnt lgkmcnt(0)" ::: "memory");
    __builtin_amdgcn_s_barrier();
}

#define PKFMA(acc, h2, w2) \
    asm("v_pk_fma_f32 %0, %1, %2, %0" : "+v"(acc) : "v"(h2), "v"(w2))

__global__ __launch_bounds__(512) __attribute__((amdgpu_waves_per_eu(2, 2)))
void lstm_scan_kernel(
    const float* __restrict__ xp0, const float* __restrict__ xp1,
    const float* __restrict__ Wh0, const float* __restrict__ Wh1,
    const int* __restrict__ x, float* __restrict__ hout)
{
    const int b   = blockIdx.x;
    const int dir = blockIdx.y;
    const float* __restrict__ xp = dir ? xp1 : xp0;
    const float* __restrict__ Wh = dir ? Wh1 : Wh0;

    const int tid = threadIdx.x;
    const int ks  = tid & 3;
    const int q   = tid >> 2;

    const float* wp = Wh + (size_t)(ks * 32) * G4 + q;
#define LDP(c, p) v2f w##c##_##p = { wp[(2 * p) * G4 + c * H], \
                                     wp[(2 * p + 1) * G4 + c * H] }
#define DECLC(c) \
    LDP(c, 0);  LDP(c, 1);  LDP(c, 2);  LDP(c, 3);  \
    LDP(c, 4);  LDP(c, 5);  LDP(c, 6);  LDP(c, 7);  \
    LDP(c, 8);  LDP(c, 9);  LDP(c, 10); LDP(c, 11); \
    LDP(c, 12); LDP(c, 13); LDP(c, 14); LDP(c, 15);
    DECLC(0) DECLC(1) DECLC(2) DECLC(3)
#undef DECLC
#undef LDP
#define PIN4(a, b_, c_, d_) asm volatile("" : "+v"(a), "+v"(b_), "+v"(c_), "+v"(d_))
#define PINC(c) \
    PIN4(w##c##_0,  w##c##_1,  w##c##_2,  w##c##_3);  \
    PIN4(w##c##_4,  w##c##_5,  w##c##_6,  w##c##_7);  \
    PIN4(w##c##_8,  w##c##_9,  w##c##_10, w##c##_11); \
    PIN4(w##c##_12, w##c##_13, w##c##_14, w##c##_15)
    PINC(0); PINC(1); PINC(2); PINC(3);
#undef PINC
#undef PIN4

    __shared__ __align__(16) float h_sh[2][4][36];
    __shared__ unsigned char mask_sh[T];

    if (tid < H) { h_sh[0][tid >> 5][tid & 31] = 0.f; }
    mask_sh[tid] = (x[(size_t)b * T + tid] != 0) ? 1 : 0;
    float c_reg = 0.f, h_reg = 0.f;
    __syncthreads();

    const int t0 = dir ? T - 1 : 0;
    const ptrdiff_t dstep = dir ? -(ptrdiff_t)G4 : (ptrdiff_t)G4;
    const ptrdiff_t hstep = dir ? -(ptrdiff_t)HOUT : (ptrdiff_t)HOUT;
    const float* xptr = xp + ((size_t)b * T + t0) * G4 + ks * H + q;
    float*       hptr = hout + ((size_t)b * T + t0) * HOUT + dir * H + q;
    float xp_cur = *xptr;

    int cb = 0;
    int t = t0;
    const int tinc = dir ? -1 : 1;

    for (int s = 0; s < T; s++) {
        float xin = xp_cur;
        if (s + 1 < T) {
            xptr += dstep;
            xp_cur = *xptr;
        }

        v2f acc0 = { (ks == 0) ? xin : 0.f, 0.f };
        v2f acc1 = { (ks == 1) ? xin : 0.f, 0.f };
        v2f acc2 = { (ks == 2) ? xin : 0.f, 0.f };
        v2f acc3 = { (ks == 3) ? xin : 0.f, 0.f };

        const v4f* hp = (const v4f*)&h_sh[cb][ks][0];
#define STEP4(kk, pA, pB) { \
        v4f hv = hp[kk]; \
        v2f h01 = __builtin_shufflevector(hv, hv, 0, 1); \
        v2f h23 = __builtin_shufflevector(hv, hv, 2, 3); \
        PKFMA(acc0, h01, w0_##pA); PKFMA(acc0, h23, w0_##pB); \
        PKFMA(acc1, h01, w1_##pA); PKFMA(acc1, h23, w1_##pB); \
        PKFMA(acc2, h01, w2_##pA); PKFMA(acc2, h23, w2_##pB); \
        PKFMA(acc3, h01, w3_##pA); PKFMA(acc3, h23, w3_##pB); }
        STEP4(0, 0, 1)   STEP4(1, 2, 3)   STEP4(2, 4, 5)   STEP4(3, 6, 7)
        STEP4(4, 8, 9)   STEP4(5, 10, 11) STEP4(6, 12, 13) STEP4(7, 14, 15)
#undef STEP4

        float a0 = acc0.x + acc0.y;
        float a1 = acc1.x + acc1.y;
        float a2 = acc2.x + acc2.y;
        float a3 = acc3.x + acc3.y;

        a0 = dpp_add<0xB1>(a0); a1 = dpp_add<0xB1>(a1);
        a2 = dpp_add<0xB1>(a2); a3 = dpp_add<0xB1>(a3);
        a0 = dpp_add<0x4E>(a0); a1 = dpp_add<0x4E>(a1);
        a2 = dpp_add<0x4E>(a2); a3 = dpp_add<0x4E>(a3);

        float ig = fast_sig(a0);
        float fg = fast_sig(a1);
        float gg = 2.f * fast_sig(a2 + a2) - 1.f;
        float og = fast_sig(a3);
        float cn = fmaf(fg, c_reg, ig * gg);
        float th = 2.f * fast_sig(cn + cn) - 1.f;
        float hn = og * th;

        bool msk = mask_sh[t] != 0;
        c_reg = msk ? cn : c_reg;
        h_reg = msk ? hn : h_reg;

        if (ks == 0) {
            h_sh[cb ^ 1][q >> 5][q & 31] = h_reg;
            *hptr = h_reg;
        }
        hptr += hstep;
        wg_barrier_lds();
        cb ^= 1;
        t += tinc;
    }
}

// ---------------------------------------------------------------------------
// 4) pooling: per (b,t) max & mean over 256 channels -> feat (B, 2T)
// ---------------------------------------------------------------------------
__global__ __launch_bounds__(256) void pool_kernel(
    const float* __restrict__ Hin, float* __restrict__ feat)
{
    int wave = threadIdx.x >> 6;
    int lane = threadIdx.x & 63;
    int bt = blockIdx.x * 4 + wave;
    float4 v = *(const float4*)&Hin[(size_t)bt * HOUT + lane * 4];
    float mx = fmaxf(fmaxf(v.x, v.y), fmaxf(v.z, v.w));
    float sm = (v.x + v.y) + (v.z + v.w);
#pragma unroll
    for (int off = 32; off > 0; off >>= 1) {
        mx = fmaxf(mx, __shfl_down(mx, off));
        sm += __shfl_down(sm, off);
    }
    if (lane == 0) {
        int b = bt >> 9;
        int t = bt & (T - 1);
        feat[(size_t)b * (2 * T) + t]     = mx;
        feat[(size_t)b * (2 * T) + T + t] = sm * (1.f / 256.f);
    }
}

// ---------------------------------------------------------------------------
// 5) FC: out(B,10) = relu(feat(B,1024) @ fcW(1024,10) + fcb)
// ---------------------------------------------------------------------------
__global__ __launch_bounds__(128) void fc_kernel(
    const float* __restrict__ feat, const float* __restrict__ fcW,
    const float* __restrict__ fcb, float* __restrict__ out)
{
    __shared__ float red[2][NUM_CLASSES];
    int b = blockIdx.x, tid = threadIdx.x;
    float acc[NUM_CLASSES];
#pragma unroll
    for (int c = 0; c < NUM_CLASSES; c++) acc[c] = 0.f;
#pragma unroll
    for (int it = 0; it < 8; it++) {
        int k = tid + it * 128;
        float fv = feat[(size_t)b * 1024 + k];
#pragma unroll
        for (int c = 0; c < NUM_CLASSES; c++)
            acc[c] = fmaf(fv, fcW[(size_t)k * NUM_CLASSES + c], acc[c]);
    }
#pragma unroll
    for (int c = 0; c < NUM_CLASSES; c++) {
        float v = acc[c];
        for (int off = 32; off > 0; off >>= 1) v += __shfl_down(v, off);
        if ((tid & 63) == 0) red[tid >> 6][c] = v;
    }
    __syncthreads();
    if (tid < NUM_CLASSES) {
        float v = red[0][tid] + red[1][tid] + fcb[tid];
        out[(size_t)b * NUM_CLASSES + tid] = fmaxf(v, 0.f);
    }
}

// ---------------------------------------------------------------------------
// launch
// ws layout (MiB): [0,32) Hbuf | [32,96) xpF | [96,160) xpB |
// [160,192) a2 | [192,193) w2t | [193,193.25) feat
// ---------------------------------------------------------------------------
extern "C" void kernel_launch(void* const* d_in, const int* in_sizes, int n_in,
                              void* d_out, int out_size, void* d_ws, size_t ws_size,
                              hipStream_t stream)
{
    const int*   x     = (const int*)d_in[0];
    const float* emb   = (const float*)d_in[1];
    const float* Wx_f0 = (const float*)d_in[2];
    const float* Wh_f0 = (const float*)d_in[3];
    const float* b_f0  = (const float*)d_in[4];
    const float* Wx_b0 = (const float*)d_in[5];
    const float* Wh_b0 = (const float*)d_in[6];
    const float* b_b0  = (const float*)d_in[7];
    const float* Wx_f1 = (const float*)d_in[8];
    const float* Wh_f1 = (const float*)d_in[9];
    const float* b_f1  = (const float*)d_in[10];
    const float* Wx_b1 = (const float*)d_in[11];
    const float* Wh_b1 = (const float*)d_in[12];
    const float* b_b1  = (const float*)d_in[13];
    const float* fcW   = (const float*)d_in[14];
    const float* fcb   = (const float*)d_in[15];
    float* out = (float*)d_out;

    char* ws = (char*)d_ws;
    const size_t MB = 1024 * 1024;
    float*          Hbuf = (float*)(ws);
    float*          xpF  = (float*)(ws + 32 * MB);
    float*          xpB  = (float*)(ws + 96 * MB);
    unsigned short* a2   = (unsigned short*)(ws + 160 * MB);
    unsigned short* w2t  = (unsigned short*)(ws + 192 * MB);
    float*          feat = (float*)(ws + 193 * MB);

    dim3 ggrid(1024 / 128, BT / 128);  // (8, 256)

    // ---- layer 0 (K = 128) ----
    prep_w2t_kernel<<<1024, 128, 0, stream>>>(Wx_f0, Wx_b0, w2t, EMBED);
    prep_a2_emb_kernel<<<BT, 128, 0, stream>>>(x, emb, a2);
    gemm_mfma_kernel<<<ggrid, 256, 0, stream>>>(a2, w2t, b_f0, b_b0, xpF, xpB, EMBED);
    lstm_scan_kernel<<<dim3(B, 2), 512, 0, stream>>>(xpF, xpB, Wh_f0, Wh_b0, x, Hbuf);

    // ---- layer 1 (K = 256) ----
    prep_w2t_kernel<<<1024, 128, 0, stream>>>(Wx_f1, Wx_b1, w2t, 2 * H);
    prep_a2_h_kernel<<<BT, 256, 0, stream>>>(Hbuf, a2);
    gemm_mfma_kernel<<<ggrid, 256, 0, stream>>>(a2, w2t, b_f1, b_b1, xpF, xpB, 2 * H);
    lstm_scan_kernel<<<dim3(B, 2), 512, 0, stream>>>(xpF, xpB, Wh_f1, Wh_b1, x, Hbuf);

    // ---- pooling + FC ----
    pool_kernel<<<BT / 4, 256, 0, stream>>>(Hbuf, feat);
    fc_kernel<<<B, 128, 0, stream>>>(feat, fcW, fcb, out);
}

// Round 15
// 863.932 us; speedup vs baseline: 5.0472x; 1.0091x over previous
//
#include <hip/hip_runtime.h>
#include <hip/hip_bf16.h>
#include <cstdint>
#include <cstddef>

#define B 64
#define T 512
#define EMBED 128
#define H 128
#define G4 512          // 4*H
#define HOUT 256        // 2*H (bilstm concat)
#define NUM_CLASSES 10
#define BT (B * T)      // 32768

typedef float v2f __attribute__((ext_vector_type(2)));
typedef float v4f __attribute__((ext_vector_type(4)));
typedef short v8s __attribute__((ext_vector_type(8)));       // 8 bf16

// ---------------------------------------------------------------------------
// bf16 split helpers (truncation; hi+lo ~ 2^-17 relative)
// ---------------------------------------------------------------------------
__device__ __forceinline__ unsigned short bf16_hi(float v) {
    return (unsigned short)(__float_as_uint(v) >> 16);
}
__device__ __forceinline__ unsigned short bf16_lo(float v, unsigned short hi) {
    float hf = __uint_as_float((unsigned)hi << 16);
    return (unsigned short)(__float_as_uint(v - hf) >> 16);
}

// ---------------------------------------------------------------------------
// 1a) prep_w2t: w2t[n][j] bf16, n in [0,1024): col n of (n<512 ? Wf : Wb).
// ---------------------------------------------------------------------------
__global__ __launch_bounds__(128) void prep_w2t_kernel(
    const float* __restrict__ Wf, const float* __restrict__ Wb,
    unsigned short* __restrict__ w2t, int K)
{
    int n = blockIdx.x;
    const float* src = (n < 512) ? (Wf + n) : (Wb + (n - 512));
    unsigned short* dst = w2t + (size_t)n * (2 * K);
    for (int j = threadIdx.x; j < K; j += 128) {
        float v = src[(size_t)j * G4];
        unsigned short hi = bf16_hi(v);
        dst[j]     = hi;
        dst[K + j] = bf16_lo(v, hi);
    }
}

// ---------------------------------------------------------------------------
// 1b) prep_a2_emb: a2[m][0..128)=hi(emb[x[m]][j]), [128..256)=lo. K=128.
// ---------------------------------------------------------------------------
__global__ __launch_bounds__(128) void prep_a2_emb_kernel(
    const int* __restrict__ x, const float* __restrict__ emb,
    unsigned short* __restrict__ a2)
{
    int m = blockIdx.x;
    int j = threadIdx.x;
    float v = emb[(size_t)x[m] * EMBED + j];
    unsigned short hi = bf16_hi(v);
    a2[(size_t)m * 256 + j]       = hi;
    a2[(size_t)m * 256 + 128 + j] = bf16_lo(v, hi);
}

// ---------------------------------------------------------------------------
// 2) MFMA GEMM (r11, unchanged): C = A @ [Wf|Wb] + bias via 3-term bf16
//    split: Ah@Wh + Ah@Wl + Al@Wh. 128x128 tile, 4 waves, 16x16x32 bf16.
// ---------------------------------------------------------------------------
__global__ __launch_bounds__(256) void gemm_mfma_kernel(
    const unsigned short* __restrict__ a2, const unsigned short* __restrict__ w2t,
    const float* __restrict__ bF, const float* __restrict__ bB,
    float* __restrict__ xpF, float* __restrict__ xpB, int K)
{
    __shared__ __align__(16) unsigned short As[128 * 40];
    __shared__ __align__(16) unsigned short Ws[128 * 40];

    const int tid  = threadIdx.x;
    const int lane = tid & 63;
    const int wv   = tid >> 6;
    const int wr   = wv >> 1;
    const int wc   = wv & 1;
    const int n0   = blockIdx.x * 128;
    const int m0   = blockIdx.y * 128;
    const int K2   = 2 * K;

    const int srow  = tid >> 1;
    const int spart = tid & 1;
    const unsigned short* agp = a2 + (size_t)(m0 + srow) * K2 + spart * 16;
    const unsigned short* wgp = w2t + (size_t)(n0 + srow) * K2 + spart * 16;
    unsigned short* alp = &As[srow * 40 + spart * 16];
    unsigned short* wlp = &Ws[srow * 40 + spart * 16];

    v4f acc[4][4];
#pragma unroll
    for (int i = 0; i < 4; i++)
#pragma unroll
        for (int j = 0; j < 4; j++) acc[i][j] = (v4f){0.f, 0.f, 0.f, 0.f};

    const int ksub = K >> 5;
    const int nsteps = 3 * ksub;
    for (int s = 0; s < nsteps; ++s) {
        int t  = s / ksub;
        int kk = s - t * ksub;
        int aoff = ((t == 2) ? K : 0) + kk * 32;
        int woff = ((t == 1) ? K : 0) + kk * 32;

        {
            v8s a0 = *(const v8s*)(agp + aoff);
            v8s a1 = *(const v8s*)(agp + aoff + 8);
            v8s w0 = *(const v8s*)(wgp + woff);
            v8s w1 = *(const v8s*)(wgp + woff + 8);
            *(v8s*)(alp)     = a0;
            *(v8s*)(alp + 8) = a1;
            *(v8s*)(wlp)     = w0;
            *(v8s*)(wlp + 8) = w1;
        }
        __syncthreads();

        v8s af[4], wf[4];
#pragma unroll
        for (int mr = 0; mr < 4; mr++)
            af[mr] = *(const v8s*)&As[(wr * 64 + mr * 16 + (lane & 15)) * 40 + (lane >> 4) * 8];
#pragma unroll
        for (int nr = 0; nr < 4; nr++)
            wf[nr] = *(const v8s*)&Ws[(wc * 64 + nr * 16 + (lane & 15)) * 40 + (lane >> 4) * 8];
#pragma unroll
        for (int mr = 0; mr < 4; mr++)
#pragma unroll
            for (int nr = 0; nr < 4; nr++)
                acc[mr][nr] = __builtin_amdgcn_mfma_f32_16x16x32_bf16(
                    af[mr], wf[nr], acc[mr][nr], 0, 0, 0);
        __syncthreads();
    }

#pragma unroll
    for (int nr = 0; nr < 4; nr++) {
        int gcol = n0 + wc * 64 + nr * 16 + (lane & 15);
        float bv = (gcol < 512) ? bF[gcol] : bB[gcol - 512];
        float* dst = (gcol < 512) ? (xpF + gcol) : (xpB + gcol - 512);
#pragma unroll
        for (int mr = 0; mr < 4; mr++) {
            int grow = m0 + wr * 64 + mr * 16 + (lane >> 4) * 4;
            v4f fr = acc[mr][nr];
#pragma unroll
            for (int r = 0; r < 4; r++)
                dst[(size_t)(grow + r) * G4] = fr[r] + bv;
        }
    }
}

// ---------------------------------------------------------------------------
// 3) LSTM scan v6 core (353 us known-good) with templated output stage:
//    OUT=0: write f32 h to hout (layer 1 -> pooling).
//    OUT=1: write bf16 hi/lo split directly into a2 (layer 0 -> layer-1
//           GEMM input), fusing away the prep_a2_h pass. Split math is
//           identical to prep_a2_h -> bit-identical a2.
//    Inner structure unchanged: 512 thr / 8 waves per (batch, direction),
//    f32 pk_fma, asm-pinned register weights, DPP butterfly, bank-disjoint
//    skewed h blocks, LDS-only barrier drain. 8 waves/CU fits the register
//    file; 1024-thr variants spill (r2/r13).
// ---------------------------------------------------------------------------
__device__ __forceinline__ float fast_sig(float x) {
    float e = __expf(-x);
    return __builtin_amdgcn_rcpf(1.f + e);
}

template <int CTRL>
__device__ __forceinline__ float dpp_add(float x) {
    int y = __builtin_amdgcn_mov_dpp(__float_as_int(x), CTRL, 0xF, 0xF, true);
    return x + __int_as_float(y);
}

__device__ __forceinline__ void wg_barrier_lds() {
    asm volatile("s_waitcnt lgkmcnt(0)" ::: "memory");
    __builtin_amdgcn_s_barrier();
}

#define PKFMA(acc, h2, w2) \
    asm("v_pk_fma_f32 %0, %1, %2, %0" : "+v"(acc) : "v"(h2), "v"(w2))

template <int OUT>
__global__ __launch_bounds__(512) __attribute__((amdgpu_waves_per_eu(2, 2)))
void lstm_scan_kernel(
    const float* __restrict__ xp0, const float* __restrict__ xp1,
    const float* __restrict__ Wh0, const float* __restrict__ Wh1,
    const int* __restrict__ x, float* __restrict__ hout,
    unsigned short* __restrict__ aout)
{
    const int b   = blockIdx.x;
    const int dir = blockIdx.y;
    const float* __restrict__ xp = dir ? xp1 : xp0;
    const float* __restrict__ Wh = dir ? Wh1 : Wh0;

    const int tid = threadIdx.x;
    const int ks  = tid & 3;
    const int q   = tid >> 2;

    const float* wp = Wh + (size_t)(ks * 32) * G4 + q;
#define LDP(c, p) v2f w##c##_##p = { wp[(2 * p) * G4 + c * H], \
                                     wp[(2 * p + 1) * G4 + c * H] }
#define DECLC(c) \
    LDP(c, 0);  LDP(c, 1);  LDP(c, 2);  LDP(c, 3);  \
    LDP(c, 4);  LDP(c, 5);  LDP(c, 6);  LDP(c, 7);  \
    LDP(c, 8);  LDP(c, 9);  LDP(c, 10); LDP(c, 11); \
    LDP(c, 12); LDP(c, 13); LDP(c, 14); LDP(c, 15);
    DECLC(0) DECLC(1) DECLC(2) DECLC(3)
#undef DECLC
#undef LDP
#define PIN4(a, b_, c_, d_) asm volatile("" : "+v"(a), "+v"(b_), "+v"(c_), "+v"(d_))
#define PINC(c) \
    PIN4(w##c##_0,  w##c##_1,  w##c##_2,  w##c##_3);  \
    PIN4(w##c##_4,  w##c##_5,  w##c##_6,  w##c##_7);  \
    PIN4(w##c##_8,  w##c##_9,  w##c##_10, w##c##_11); \
    PIN4(w##c##_12, w##c##_13, w##c##_14, w##c##_15)
    PINC(0); PINC(1); PINC(2); PINC(3);
#undef PINC
#undef PIN4

    __shared__ __align__(16) float h_sh[2][4][36];
    __shared__ unsigned char mask_sh[T];

    if (tid < H) { h_sh[0][tid >> 5][tid & 31] = 0.f; }
    mask_sh[tid] = (x[(size_t)b * T + tid] != 0) ? 1 : 0;
    float c_reg = 0.f, h_reg = 0.f;
    __syncthreads();

    const int t0 = dir ? T - 1 : 0;
    const ptrdiff_t dstep = dir ? -(ptrdiff_t)G4 : (ptrdiff_t)G4;
    const float* xptr = xp + ((size_t)b * T + t0) * G4 + ks * H + q;
    float xp_cur = *xptr;

    // output pointers (advance per step)
    const ptrdiff_t hstep  = dir ? -(ptrdiff_t)HOUT : (ptrdiff_t)HOUT;
    const ptrdiff_t astep  = dir ? -(ptrdiff_t)(2 * HOUT) : (ptrdiff_t)(2 * HOUT);
    float*          hptr = hout ? hout + ((size_t)b * T + t0) * HOUT + dir * H + q : nullptr;
    unsigned short* aptr = aout ? aout + ((size_t)b * T + t0) * (2 * HOUT) + dir * H + q : nullptr;

    int cb = 0;
    int t = t0;
    const int tinc = dir ? -1 : 1;

    for (int s = 0; s < T; s++) {
        float xin = xp_cur;
        if (s + 1 < T) {
            xptr += dstep;
            xp_cur = *xptr;
        }

        v2f acc0 = { (ks == 0) ? xin : 0.f, 0.f };
        v2f acc1 = { (ks == 1) ? xin : 0.f, 0.f };
        v2f acc2 = { (ks == 2) ? xin : 0.f, 0.f };
        v2f acc3 = { (ks == 3) ? xin : 0.f, 0.f };

        const v4f* hp = (const v4f*)&h_sh[cb][ks][0];
#define STEP4(kk, pA, pB) { \
        v4f hv = hp[kk]; \
        v2f h01 = __builtin_shufflevector(hv, hv, 0, 1); \
        v2f h23 = __builtin_shufflevector(hv, hv, 2, 3); \
        PKFMA(acc0, h01, w0_##pA); PKFMA(acc0, h23, w0_##pB); \
        PKFMA(acc1, h01, w1_##pA); PKFMA(acc1, h23, w1_##pB); \
        PKFMA(acc2, h01, w2_##pA); PKFMA(acc2, h23, w2_##pB); \
        PKFMA(acc3, h01, w3_##pA); PKFMA(acc3, h23, w3_##pB); }
        STEP4(0, 0, 1)   STEP4(1, 2, 3)   STEP4(2, 4, 5)   STEP4(3, 6, 7)
        STEP4(4, 8, 9)   STEP4(5, 10, 11) STEP4(6, 12, 13) STEP4(7, 14, 15)
#undef STEP4

        float a0 = acc0.x + acc0.y;
        float a1 = acc1.x + acc1.y;
        float a2v = acc2.x + acc2.y;
        float a3 = acc3.x + acc3.y;

        a0 = dpp_add<0xB1>(a0); a1 = dpp_add<0xB1>(a1);
        a2v = dpp_add<0xB1>(a2v); a3 = dpp_add<0xB1>(a3);
        a0 = dpp_add<0x4E>(a0); a1 = dpp_add<0x4E>(a1);
        a2v = dpp_add<0x4E>(a2v); a3 = dpp_add<0x4E>(a3);

        float ig = fast_sig(a0);
        float fg = fast_sig(a1);
        float gg = 2.f * fast_sig(a2v + a2v) - 1.f;
        float og = fast_sig(a3);
        float cn = fmaf(fg, c_reg, ig * gg);
        float th = 2.f * fast_sig(cn + cn) - 1.f;
        float hn = og * th;

        bool msk = mask_sh[t] != 0;
        c_reg = msk ? cn : c_reg;
        h_reg = msk ? hn : h_reg;

        if (ks == 0) {
            h_sh[cb ^ 1][q >> 5][q & 31] = h_reg;
            if constexpr (OUT == 0) {
                *hptr = h_reg;
            } else {
                unsigned short hi = bf16_hi(h_reg);
                aptr[0]    = hi;
                aptr[HOUT] = bf16_lo(h_reg, hi);   // lo half at +256
            }
        }
        if constexpr (OUT == 0) hptr += hstep; else aptr += astep;
        wg_barrier_lds();
        cb ^= 1;
        t += tinc;
    }
}

// ---------------------------------------------------------------------------
// 4) pooling: per (b,t) max & mean over 256 channels -> feat (B, 2T)
// ---------------------------------------------------------------------------
__global__ __launch_bounds__(256) void pool_kernel(
    const float* __restrict__ Hin, float* __restrict__ feat)
{
    int wave = threadIdx.x >> 6;
    int lane = threadIdx.x & 63;
    int bt = blockIdx.x * 4 + wave;
    float4 v = *(const float4*)&Hin[(size_t)bt * HOUT + lane * 4];
    float mx = fmaxf(fmaxf(v.x, v.y), fmaxf(v.z, v.w));
    float sm = (v.x + v.y) + (v.z + v.w);
#pragma unroll
    for (int off = 32; off > 0; off >>= 1) {
        mx = fmaxf(mx, __shfl_down(mx, off));
        sm += __shfl_down(sm, off);
    }
    if (lane == 0) {
        int b = bt >> 9;
        int t = bt & (T - 1);
        feat[(size_t)b * (2 * T) + t]     = mx;
        feat[(size_t)b * (2 * T) + T + t] = sm * (1.f / 256.f);
    }
}

// ---------------------------------------------------------------------------
// 5) FC: out(B,10) = relu(feat(B,1024) @ fcW(1024,10) + fcb)
// ---------------------------------------------------------------------------
__global__ __launch_bounds__(128) void fc_kernel(
    const float* __restrict__ feat, const float* __restrict__ fcW,
    const float* __restrict__ fcb, float* __restrict__ out)
{
    __shared__ float red[2][NUM_CLASSES];
    int b = blockIdx.x, tid = threadIdx.x;
    float acc[NUM_CLASSES];
#pragma unroll
    for (int c = 0; c < NUM_CLASSES; c++) acc[c] = 0.f;
#pragma unroll
    for (int it = 0; it < 8; it++) {
        int k = tid + it * 128;
        float fv = feat[(size_t)b * 1024 + k];
#pragma unroll
        for (int c = 0; c < NUM_CLASSES; c++)
            acc[c] = fmaf(fv, fcW[(size_t)k * NUM_CLASSES + c], acc[c]);
    }
#pragma unroll
    for (int c = 0; c < NUM_CLASSES; c++) {
        float v = acc[c];
        for (int off = 32; off > 0; off >>= 1) v += __shfl_down(v, off);
        if ((tid & 63) == 0) red[tid >> 6][c] = v;
    }
    __syncthreads();
    if (tid < NUM_CLASSES) {
        float v = red[0][tid] + red[1][tid] + fcb[tid];
        out[(size_t)b * NUM_CLASSES + tid] = fmaxf(v, 0.f);
    }
}

// ---------------------------------------------------------------------------
// launch
// ws layout (MiB): [0,32) Hbuf | [32,96) xpF | [96,160) xpB |
// [160,192) a2 | [192,193) w2t | [193,193.25) feat
// ---------------------------------------------------------------------------
extern "C" void kernel_launch(void* const* d_in, const int* in_sizes, int n_in,
                              void* d_out, int out_size, void* d_ws, size_t ws_size,
                              hipStream_t stream)
{
    const int*   x     = (const int*)d_in[0];
    const float* emb   = (const float*)d_in[1];
    const float* Wx_f0 = (const float*)d_in[2];
    const float* Wh_f0 = (const float*)d_in[3];
    const float* b_f0  = (const float*)d_in[4];
    const float* Wx_b0 = (const float*)d_in[5];
    const float* Wh_b0 = (const float*)d_in[6];
    const float* b_b0  = (const float*)d_in[7];
    const float* Wx_f1 = (const float*)d_in[8];
    const float* Wh_f1 = (const float*)d_in[9];
    const float* b_f1  = (const float*)d_in[10];
    const float* Wx_b1 = (const float*)d_in[11];
    const float* Wh_b1 = (const float*)d_in[12];
    const float* b_b1  = (const float*)d_in[13];
    const float* fcW   = (const float*)d_in[14];
    const float* fcb   = (const float*)d_in[15];
    float* out = (float*)d_out;

    char* ws = (char*)d_ws;
    const size_t MB = 1024 * 1024;
    float*          Hbuf = (float*)(ws);
    float*          xpF  = (float*)(ws + 32 * MB);
    float*          xpB  = (float*)(ws + 96 * MB);
    unsigned short* a2   = (unsigned short*)(ws + 160 * MB);
    unsigned short* w2t  = (unsigned short*)(ws + 192 * MB);
    float*          feat = (float*)(ws + 193 * MB);

    dim3 ggrid(1024 / 128, BT / 128);  // (8, 256)

    // ---- layer 0 (K = 128); scan writes split-bf16 a2 directly ----
    prep_w2t_kernel<<<1024, 128, 0, stream>>>(Wx_f0, Wx_b0, w2t, EMBED);
    prep_a2_emb_kernel<<<BT, 128, 0, stream>>>(x, emb, a2);
    gemm_mfma_kernel<<<ggrid, 256, 0, stream>>>(a2, w2t, b_f0, b_b0, xpF, xpB, EMBED);
    lstm_scan_kernel<1><<<dim3(B, 2), 512, 0, stream>>>(
        xpF, xpB, Wh_f0, Wh_b0, x, nullptr, a2);

    // ---- layer 1 (K = 256); a2 already populated by layer-0 scan ----
    prep_w2t_kernel<<<1024, 128, 0, stream>>>(Wx_f1, Wx_b1, w2t, 2 * H);
    gemm_mfma_kernel<<<ggrid, 256, 0, stream>>>(a2, w2t, b_f1, b_b1, xpF, xpB, 2 * H);
    lstm_scan_kernel<0><<<dim3(B, 2), 512, 0, stream>>>(
        xpF, xpB, Wh_f1, Wh_b1, x, Hbuf, nullptr);

    // ---- pooling + FC ----
    pool_kernel<<<BT / 4, 256, 0, stream>>>(Hbuf, feat);
    fc_kernel<<<B, 128, 0, stream>>>(feat, fcW, fcb, out);
}